// Round 1
// 1222.783 us; speedup vs baseline: 2.0295x; 2.0295x over previous
//
#include <hip/hip_runtime.h>
#include <float.h>

#define D_    768
#define GD    64
#define PD    256
#define HH    12
#define HDD   64
#define NGP   (GD*PD)   // 16384
#define SCALE 0.125f

typedef __bf16 bf16x8 __attribute__((ext_vector_type(8)));
typedef __bf16 bf16x4 __attribute__((ext_vector_type(4)));
typedef _Float16 f16x8 __attribute__((ext_vector_type(8)));
typedef _Float16 f16x4 __attribute__((ext_vector_type(4)));
typedef float  f32x4  __attribute__((ext_vector_type(4)));

__device__ __forceinline__ void gload_lds16(const __bf16* g, __bf16* l) {
  __builtin_amdgcn_global_load_lds(
      (const __attribute__((address_space(1))) void*)g,
      (__attribute__((address_space(3))) void*)l, 16, 0, 0);
}

__device__ __forceinline__ unsigned short f2bf_bits(float f) {
  __bf16 h = (__bf16)f;
  unsigned short u;
  __builtin_memcpy(&u, &h, 2);
  return u;
}

// ---------------- fp32 -> bf16 elementwise cast (weights) ----------------
__global__ void wcast_k(const float* __restrict__ in, __bf16* __restrict__ out, int n) {
  int i = (blockIdx.x * 256 + threadIdx.x) * 4;
  if (i >= n) return;
  float4 v = *(const float4*)(in + i);
  bf16x4 o;
  o[0] = (__bf16)v.x; o[1] = (__bf16)v.y; o[2] = (__bf16)v.z; o[3] = (__bf16)v.w;
  *(bf16x4*)(out + i) = o;
}

// ---------------- transpose-cast: in[768][16384] f32 -> out[16384][768] bf16 ----------------
__global__ void tcast_k(const float* __restrict__ in, __bf16* __restrict__ out) {
  __shared__ float s[32][66];
  const int tid = threadIdx.x;
  const int c0 = blockIdx.x * 64;
  const int r0 = blockIdx.y * 32;
  const int lx = tid & 63, ly = tid >> 6;
  #pragma unroll
  for (int rr = 0; rr < 32; rr += 4)
    s[rr + ly][lx] = in[(size_t)(r0 + rr + ly) * NGP + c0 + lx];
  __syncthreads();
  const int wx = tid & 15, wy = tid >> 4;
  unsigned* outu = (unsigned*)out;
  #pragma unroll
  for (int p = 0; p < 64; p += 16) {
    int j = p + wy;
    unsigned pk = (unsigned)f2bf_bits(s[2*wx][j]) |
                  ((unsigned)f2bf_bits(s[2*wx+1][j]) << 16);
    outu[(size_t)(c0 + j) * (D_/2) + (r0 >> 1) + wx] = pk;
  }
}

// ---------------- MFMA GEMM: C[M,N] = A[M,K] * Bt[N,K]^T (+bias) ----------------
// OUT: 0=f32, 1=bf16, 2=f16
template<int BIAS, int OUT>
__global__ __launch_bounds__(256, 2)
void mfma_gemm(const __bf16* __restrict__ A, const __bf16* __restrict__ Bt,
               const float* __restrict__ bias, void* __restrict__ Cout,
               int M, int N, int K) {
  __shared__ __align__(16) __bf16 As[128 * 32];
  __shared__ __align__(16) __bf16 Bs[128 * 32];
  const int tid = threadIdx.x;
  const int wave = tid >> 6, lane = tid & 63;
  const int wm = wave >> 1, wn = wave & 1;
  const int m0 = blockIdx.y * 128, n0 = blockIdx.x * 128;

  const int r0g = wave * 2, r1g = wave * 2 + 1;
  const int kch = (lane >> 4) * 8;
  const __bf16* gA0 = A  + (size_t)(m0 + r0g * 16 + (lane & 15)) * K + kch;
  const __bf16* gA1 = gA0 + (size_t)16 * K;
  const __bf16* gB0 = Bt + (size_t)(n0 + r0g * 16 + (lane & 15)) * K + kch;
  const __bf16* gB1 = gB0 + (size_t)16 * K;
  __bf16* lA0 = As + r0g * 512;  __bf16* lA1 = As + r1g * 512;
  __bf16* lB0 = Bs + r0g * 512;  __bf16* lB1 = Bs + r1g * 512;

  f32x4 acc[4][4] = {};
  const bf16x8* Av = (const bf16x8*)As;
  const bf16x8* Bv = (const bf16x8*)Bs;

  for (int k0 = 0; k0 < K; k0 += 32) {
    __syncthreads();
    gload_lds16(gA0, lA0); gload_lds16(gA1, lA1);
    gload_lds16(gB0, lB0); gload_lds16(gB1, lB1);
    gA0 += 32; gA1 += 32; gB0 += 32; gB1 += 32;
    __syncthreads();
    bf16x8 af[4], bf[4];
    #pragma unroll
    for (int i = 0; i < 4; ++i) af[i] = Av[(wm * 4 + i) * 64 + lane];
    #pragma unroll
    for (int j = 0; j < 4; ++j) bf[j] = Bv[(wn * 4 + j) * 64 + lane];
    #pragma unroll
    for (int i = 0; i < 4; ++i)
      #pragma unroll
      for (int j = 0; j < 4; ++j)
        acc[i][j] = __builtin_amdgcn_mfma_f32_16x16x32_bf16(af[i], bf[j], acc[i][j], 0, 0, 0);
  }

  #pragma unroll
  for (int i = 0; i < 4; ++i) {
    #pragma unroll
    for (int j = 0; j < 4; ++j) {
      const int col  = n0 + wn * 64 + j * 16 + (lane & 15);
      const int row0 = m0 + wm * 64 + i * 16 + (lane >> 4) * 4;
      #pragma unroll
      for (int r = 0; r < 4; ++r) {
        float v = acc[i][j][r];
        if (BIAS) v += bias[row0 + r];
        if (OUT == 1)
          ((__bf16*)Cout)[(size_t)(row0 + r) * N + col] = (__bf16)v;
        else if (OUT == 2)
          ((_Float16*)Cout)[(size_t)(row0 + r) * N + col] = (_Float16)v;
        else
          ((float*)Cout)[(size_t)(row0 + r) * N + col] = v;
      }
    }
  }
}

// ---------------- MFMA flash attention ----------------
// qkT [16384][1536] bf16 (q|k channels, row = g*256+p), vbuf [768][16384] f16.
// One block per (g,h); 4 waves, wave owns 64 p-columns. Swapped operands:
//   S^T = K . Q^T   (D: row=q, col=p=lane&15+16j  -> softmax stats per-lane-column)
//   O^T = V^T . P^T (D: row=hd (4-consecutive per reg), col=p -> packs into aot[gp][ch])
// P goes through per-wave LDS (m97 chunk layout: lane-linear, conflict-free reads).
__global__ __launch_bounds__(256, 2)
void attn_mfma(const __bf16* __restrict__ qkT, const _Float16* __restrict__ vbuf,
               const unsigned char* __restrict__ mask, __bf16* __restrict__ aot) {
  __shared__ unsigned mb[256][8];                    // mask bitmap [p][q/32], 8 KB
  __shared__ __align__(16) _Float16 p_lds[4][4096];  // per-wave P tile, 32 KB

  const int g = blockIdx.x, h = blockIdx.y;
  const int tid = threadIdx.x;
  const int wave = tid >> 6, lane = tid & 63;
  const int l15 = lane & 15, t4 = lane >> 4;

  // Q fragments (B-operand Bt[p][hd]) — resident all kernel
  const __bf16* qbase = qkT + (size_t)(g*PD + wave*64 + l15) * 1536 + h*HDD + t4*8;
  bf16x8 qf[4][2];
  #pragma unroll
  for (int j = 0; j < 4; ++j)
    #pragma unroll
    for (int ks = 0; ks < 2; ++ks)
      qf[j][ks] = *(const bf16x8*)(qbase + (size_t)j*16*1536 + ks*32);

  // mask -> bitmask (thread t handles row p=t); dtype detect i32 vs bytes
  const unsigned* mwords = (const unsigned*)mask;
  bool is_i32 = true;
  #pragma unroll
  for (int i = 0; i < 16; ++i) is_i32 = is_i32 && (mwords[i] <= 1u);
  if (is_i32) {
    const uint4* mr4 = (const uint4*)(mwords + ((size_t)g*PD + tid)*PD);
    #pragma unroll
    for (int w = 0; w < 8; ++w) {
      unsigned bits = 0;
      #pragma unroll
      for (int j = 0; j < 8; ++j) {
        uint4 m4 = mr4[w*8 + j];
        bits |= (m4.x ? 1u : 0u) << (j*4+0);
        bits |= (m4.y ? 1u : 0u) << (j*4+1);
        bits |= (m4.z ? 1u : 0u) << (j*4+2);
        bits |= (m4.w ? 1u : 0u) << (j*4+3);
      }
      mb[tid][w] = bits;
    }
  } else {
    const unsigned* mr = (const unsigned*)(mask + ((size_t)g*PD + tid)*PD);
    #pragma unroll
    for (int w = 0; w < 8; ++w) {
      unsigned bits = 0;
      #pragma unroll
      for (int j = 0; j < 8; ++j) {
        unsigned vv = mr[w*8 + j];
        if (vv & 0x000000FFu) bits |= 1u << (j*4+0);
        if (vv & 0x0000FF00u) bits |= 1u << (j*4+1);
        if (vv & 0x00FF0000u) bits |= 1u << (j*4+2);
        if (vv & 0xFF000000u) bits |= 1u << (j*4+3);
      }
      mb[tid][w] = bits;
    }
  }
  __syncthreads();   // only barrier in the kernel

  const __bf16* kbase = qkT + (size_t)(g*PD + l15) * 1536 + D_ + h*HDD + t4*8;
  const _Float16* vb  = vbuf + (size_t)(h*HDD + l15) * NGP + g*PD + t4*8;
  _Float16* pw = &p_lds[wave][0];

  float rm[4], rl[4];
  #pragma unroll
  for (int j = 0; j < 4; ++j) { rm[j] = -1e30f; rl[j] = 0.f; }
  f32x4 o[4][4] = {};   // [hd-frag][p-frag]

  for (int qt = 0; qt < 4; ++qt) {
    // ---- S^T tile = K . Q^T ----
    bf16x8 kf[4][2];
    #pragma unroll
    for (int i = 0; i < 4; ++i)
      #pragma unroll
      for (int ks = 0; ks < 2; ++ks)
        kf[i][ks] = *(const bf16x8*)(kbase + (size_t)(qt*64 + i*16)*1536 + ks*32);
    f32x4 s[4][4] = {};  // [q-frag][p-frag]
    #pragma unroll
    for (int ks = 0; ks < 2; ++ks)
      #pragma unroll
      for (int i = 0; i < 4; ++i)
        #pragma unroll
        for (int j = 0; j < 4; ++j)
          s[i][j] = __builtin_amdgcn_mfma_f32_16x16x32_bf16(kf[i][ks], qf[j][ks], s[i][j], 0, 0, 0);

    // ---- masked online softmax per p-column (j, l15); q spans (i, t4, r) ----
    #pragma unroll
    for (int j = 0; j < 4; ++j) {
      const int pl = wave*64 + j*16 + l15;
      const unsigned w0 = mb[pl][qt*2 + 0], w1 = mb[pl][qt*2 + 1];
      float mxj = -1e30f;
      #pragma unroll
      for (int i = 0; i < 4; ++i) {
        const unsigned w = (i < 2) ? w0 : w1;
        const int base = (i & 1)*16 + t4*4;
        #pragma unroll
        for (int r = 0; r < 4; ++r) {
          float sv = ((w >> (base + r)) & 1u) ? s[i][j][r] : -1e30f;
          s[i][j][r] = sv;
          mxj = fmaxf(mxj, sv);
        }
      }
      mxj = fmaxf(mxj, __shfl_xor(mxj, 16, 64));
      mxj = fmaxf(mxj, __shfl_xor(mxj, 32, 64));
      const float mnew = fmaxf(rm[j], mxj);
      const float scl  = __expf((rm[j] - mnew) * SCALE);   // raw-s max; SCALE folded into exp
      const float mneg = -mnew * SCALE;
      rm[j] = mnew;
      float rs = 0.f;
      #pragma unroll
      for (int i = 0; i < 4; ++i)
        #pragma unroll
        for (int r = 0; r < 4; ++r) {
          float e = __expf(fmaf(s[i][j][r], SCALE, mneg));  // masked: arg ~ -1e29 -> 0
          s[i][j][r] = e;
          rs += e;
        }
      rs += __shfl_xor(rs, 16, 64);
      rs += __shfl_xor(rs, 32, 64);
      rl[j] = fmaf(rl[j], scl, rs);
      #pragma unroll
      for (int i2 = 0; i2 < 4; ++i2)
        #pragma unroll
        for (int r = 0; r < 4; ++r)
          o[i2][j][r] *= scl;
      // P column-block j -> LDS f16, chunk layout: addr=(qchunk*16+p15)*8 + (q&7)
      #pragma unroll
      for (int i = 0; i < 4; ++i) {
        f16x4 pk;
        #pragma unroll
        for (int r = 0; r < 4; ++r) pk[r] = (_Float16)s[i][j][r];
        *(f16x4*)&pw[j*1024 + (2*i + (t4 >> 1))*128 + l15*8 + 4*(t4 & 1)] = pk;
      }
    }

    // ---- O^T += V^T . P^T ---- (per-wave LDS: in-order DS makes RAW safe, no barrier)
    f16x8 vf[4][2], pf[4][2];
    #pragma unroll
    for (int i2 = 0; i2 < 4; ++i2)
      #pragma unroll
      for (int ks = 0; ks < 2; ++ks)
        vf[i2][ks] = *(const f16x8*)(vb + (size_t)i2*16*NGP + qt*64 + ks*32);
    #pragma unroll
    for (int j2 = 0; j2 < 4; ++j2)
      #pragma unroll
      for (int ks = 0; ks < 2; ++ks)
        pf[j2][ks] = *(const f16x8*)&pw[j2*1024 + (4*ks + t4)*128 + l15*8];
    #pragma unroll
    for (int ks = 0; ks < 2; ++ks)
      #pragma unroll
      for (int i2 = 0; i2 < 4; ++i2)
        #pragma unroll
        for (int j2 = 0; j2 < 4; ++j2)
          o[i2][j2] = __builtin_amdgcn_mfma_f32_16x16x32_f16(vf[i2][ks], pf[j2][ks], o[i2][j2], 0, 0, 0);
  }

  // ---- epilogue: O^T rows hd=16*i2+4*t4+r (consecutive r) -> 8B stores in aot[gp][ch] ----
  #pragma unroll
  for (int j2 = 0; j2 < 4; ++j2) {
    const float inv = 1.f / rl[j2];
    __bf16* ao = aot + (size_t)(g*PD + wave*64 + j2*16 + l15) * D_ + h*HDD;
    #pragma unroll
    for (int i2 = 0; i2 < 4; ++i2) {
      bf16x4 ov;
      #pragma unroll
      for (int r = 0; r < 4; ++r) ov[r] = (__bf16)(o[i2][j2][r] * inv);
      *(bf16x4*)(ao + i2*16 + t4*4) = ov;
    }
  }
}

extern "C" void kernel_launch(void* const* d_in, const int* in_sizes, int n_in,
                              void* d_out, int out_size, void* d_ws, size_t ws_size,
                              hipStream_t stream) {
  const float* x      = (const float*)d_in[0];
  const unsigned char* mask = (const unsigned char*)d_in[1];
  const float* w_qkv  = (const float*)d_in[2];
  const float* w_proj = (const float*)d_in[3];
  const float* b_proj = (const float*)d_in[4];
  float* out = (float*)d_out;

  // workspace layout (same 130.6 MB total as previous version)
  char* ws = (char*)d_ws;
  __bf16*   qkT  = (__bf16*)ws;    ws += (size_t)NGP * 1536 * 2;  // 50.3 MB [gp][1536] bf16
  _Float16* vf16 = (_Float16*)ws;  ws += (size_t)D_ * NGP * 2;    // 25.2 MB [768][gp] f16
  __bf16*   xt   = (__bf16*)ws;    ws += (size_t)NGP * D_ * 2;    // 25.2 MB
  __bf16*   aot  = (__bf16*)ws;    ws += (size_t)NGP * D_ * 2;    // 25.2 MB
  __bf16*   wq_bf= (__bf16*)ws;    ws += (size_t)3 * D_ * D_ * 2; //  3.5 MB
  __bf16*   wp_bf= (__bf16*)ws;                                   //  1.2 MB

  wcast_k<<<(3*D_*D_)/1024, 256, 0, stream>>>(w_qkv,  wq_bf, 3*D_*D_);
  wcast_k<<<(D_*D_)/1024,   256, 0, stream>>>(w_proj, wp_bf, D_*D_);

  for (int b = 0; b < 4; ++b) {
    const float* xb = x + (size_t)b * D_ * NGP;
    float* ob = out + (size_t)b * D_ * NGP;
    tcast_k<<<dim3(NGP/64, D_/32), 256, 0, stream>>>(xb, xt);
    // qkT[gp][1536] = xt[gp][d] . w_qk[1536][d]^T   (Q,K transposed for attention A/B ops)
    mfma_gemm<0,1><<<dim3(1536/128, NGP/128), 256, 0, stream>>>(xt, wq_bf, nullptr, qkT, NGP, 1536, D_);
    // v[768][gp] f16 = w_v[768][d] . xt[gp][d]^T    (channel-major: PV A-operand layout)
    mfma_gemm<0,2><<<dim3(NGP/128, D_/128), 256, 0, stream>>>(wq_bf + (size_t)1536*D_, xt, nullptr, vf16, D_, NGP, D_);
    attn_mfma<<<dim3(GD, HH), 256, 0, stream>>>(qkT, vf16, mask, aot);
    mfma_gemm<1,0><<<dim3(NGP/128, D_/128), 256, 0, stream>>>(wp_bf, aot, b_proj, ob, D_, NGP, D_);
  }
}

// Round 3
// 1182.743 us; speedup vs baseline: 2.0982x; 1.0339x over previous
//
#include <hip/hip_runtime.h>
#include <float.h>

#define D_    768
#define GD    64
#define PD    256
#define HH    12
#define HDD   64
#define NGP   (GD*PD)   // 16384
#define NB    4
#define SCALE 0.125f
#define QPRE  (0.125f * 1.44269504f)   // SCALE*log2(e), folded into Q weights

typedef __bf16 bf16x8 __attribute__((ext_vector_type(8)));
typedef __bf16 bf16x4 __attribute__((ext_vector_type(4)));
typedef _Float16 f16x8 __attribute__((ext_vector_type(8)));
typedef _Float16 f16x4 __attribute__((ext_vector_type(4)));
typedef float  f32x4  __attribute__((ext_vector_type(4)));

__device__ __forceinline__ float exp2_fast(float x) {
  return __builtin_amdgcn_exp2f(x);   // v_exp_f32: native 2^x
}

__device__ __forceinline__ void gload_lds16(const __bf16* g, __bf16* l) {
  __builtin_amdgcn_global_load_lds(
      (const __attribute__((address_space(1))) void*)g,
      (__attribute__((address_space(3))) void*)l, 16, 0, 0);
}

__device__ __forceinline__ unsigned short f2bf_bits(float f) {
  __bf16 h = (__bf16)f;
  unsigned short u;
  __builtin_memcpy(&u, &h, 2);
  return u;
}

// ---------------- fp32 -> bf16 cast; first nscale elements premultiplied by sc ----------------
__global__ void wcast_k(const float* __restrict__ in, __bf16* __restrict__ out, int n,
                        int nscale, float sc) {
  int i = (blockIdx.x * 256 + threadIdx.x) * 4;
  if (i >= n) return;
  float s = (i < nscale) ? sc : 1.f;
  float4 v = *(const float4*)(in + i);
  bf16x4 o;
  o[0] = (__bf16)(v.x * s); o[1] = (__bf16)(v.y * s);
  o[2] = (__bf16)(v.z * s); o[3] = (__bf16)(v.w * s);
  *(bf16x4*)(out + i) = o;
}

// ---------------- transpose-cast: in[768][16384] f32 -> out[16384][768] bf16 (per batch z) ----------------
__global__ void tcast_k(const float* __restrict__ in, __bf16* __restrict__ out) {
  __shared__ float s[32][66];
  const int tid = threadIdx.x;
  const int c0 = blockIdx.x * 64;
  const int r0 = blockIdx.y * 32;
  const float* inz = in + (size_t)blockIdx.z * D_ * NGP;
  unsigned* outu = (unsigned*)out + (size_t)blockIdx.z * NGP * (D_ / 2);
  const int lx = tid & 63, ly = tid >> 6;
  #pragma unroll
  for (int rr = 0; rr < 32; rr += 4)
    s[rr + ly][lx] = inz[(size_t)(r0 + rr + ly) * NGP + c0 + lx];
  __syncthreads();
  const int wx = tid & 15, wy = tid >> 4;
  #pragma unroll
  for (int p = 0; p < 64; p += 16) {
    int j = p + wy;
    unsigned pk = (unsigned)f2bf_bits(s[2*wx][j]) |
                  ((unsigned)f2bf_bits(s[2*wx+1][j]) << 16);
    outu[(size_t)(c0 + j) * (D_/2) + (r0 >> 1) + wx] = pk;
  }
}

// ---------------- MFMA GEMM: C[M,N] = A[M,K] * Bt[N,K]^T (+bias) ----------------
// OUT: 0=f32, 1=bf16, 2=f16. OUTB: remap col c -> out[b= c>>14][row][gp= c&16383] (f32 only).
template<int BIAS, int OUT, int OUTB>
__global__ __launch_bounds__(256, 2)
void mfma_gemm(const __bf16* __restrict__ A, const __bf16* __restrict__ Bt,
               const float* __restrict__ bias, void* __restrict__ Cout,
               int M, int N, int K) {
  __shared__ __align__(16) __bf16 As[128 * 32];
  __shared__ __align__(16) __bf16 Bs[128 * 32];
  const int tid = threadIdx.x;
  const int wave = tid >> 6, lane = tid & 63;
  const int wm = wave >> 1, wn = wave & 1;
  const int m0 = blockIdx.y * 128, n0 = blockIdx.x * 128;

  const int r0g = wave * 2, r1g = wave * 2 + 1;
  const int kch = (lane >> 4) * 8;
  const __bf16* gA0 = A  + (size_t)(m0 + r0g * 16 + (lane & 15)) * K + kch;
  const __bf16* gA1 = gA0 + (size_t)16 * K;
  const __bf16* gB0 = Bt + (size_t)(n0 + r0g * 16 + (lane & 15)) * K + kch;
  const __bf16* gB1 = gB0 + (size_t)16 * K;
  __bf16* lA0 = As + r0g * 512;  __bf16* lA1 = As + r1g * 512;
  __bf16* lB0 = Bs + r0g * 512;  __bf16* lB1 = Bs + r1g * 512;

  f32x4 acc[4][4] = {};
  const bf16x8* Av = (const bf16x8*)As;
  const bf16x8* Bv = (const bf16x8*)Bs;

  for (int k0 = 0; k0 < K; k0 += 32) {
    __syncthreads();
    gload_lds16(gA0, lA0); gload_lds16(gA1, lA1);
    gload_lds16(gB0, lB0); gload_lds16(gB1, lB1);
    gA0 += 32; gA1 += 32; gB0 += 32; gB1 += 32;
    __syncthreads();
    bf16x8 af[4], bf[4];
    #pragma unroll
    for (int i = 0; i < 4; ++i) af[i] = Av[(wm * 4 + i) * 64 + lane];
    #pragma unroll
    for (int j = 0; j < 4; ++j) bf[j] = Bv[(wn * 4 + j) * 64 + lane];
    #pragma unroll
    for (int i = 0; i < 4; ++i)
      #pragma unroll
      for (int j = 0; j < 4; ++j)
        acc[i][j] = __builtin_amdgcn_mfma_f32_16x16x32_bf16(af[i], bf[j], acc[i][j], 0, 0, 0);
  }

  #pragma unroll
  for (int i = 0; i < 4; ++i) {
    #pragma unroll
    for (int j = 0; j < 4; ++j) {
      const int col  = n0 + wn * 64 + j * 16 + (lane & 15);
      const int row0 = m0 + wm * 64 + i * 16 + (lane >> 4) * 4;
      #pragma unroll
      for (int r = 0; r < 4; ++r) {
        float v = acc[i][j][r];
        if (BIAS) v += bias[row0 + r];
        if (OUT == 1)
          ((__bf16*)Cout)[(size_t)(row0 + r) * N + col] = (__bf16)v;
        else if (OUT == 2)
          ((_Float16*)Cout)[(size_t)(row0 + r) * N + col] = (_Float16)v;
        else if (OUTB) {
          const int bb = col >> 14, gp = col & (NGP - 1);
          ((float*)Cout)[((size_t)bb * D_ + row0 + r) * NGP + gp] = v;
        } else
          ((float*)Cout)[(size_t)(row0 + r) * N + col] = v;
      }
    }
  }
}

// ---------------- MFMA flash attention ----------------
// qkT [b][16384][1536] bf16 (Q channels pre-scaled by SCALE*log2e), vbuf [768][vcols] f16.
// Block (g,h,b); 4 waves, wave owns 64 p-columns. Swapped operands:
//   S^T = K . Q^T   (softmax stats per lane-column, log2 domain)
//   O^T = V^T . P^T (rows hd -> packs into aot[gp][ch])
__global__ __launch_bounds__(256, 2)
void attn_mfma(const __bf16* __restrict__ qkT, const _Float16* __restrict__ vbuf,
               const unsigned char* __restrict__ mask, __bf16* __restrict__ aot,
               int vcols) {
  __shared__ unsigned mb[256][9];                    // [p][q/32] bitmap, padded stride
  __shared__ __align__(16) _Float16 p_lds[4][4096];  // per-wave P tile

  const int g = blockIdx.x, h = blockIdx.y, b = blockIdx.z;
  const int tid = threadIdx.x;
  const int wave = tid >> 6, lane = tid & 63;
  const int l15 = lane & 15, t4 = lane >> 4;

  const __bf16* qk = qkT + (size_t)b * NGP * 1536;

  // Q fragments (B-operand) — resident all kernel
  const __bf16* qbase = qk + (size_t)(g*PD + wave*64 + l15) * 1536 + h*HDD + t4*8;
  bf16x8 qf[4][2];
  #pragma unroll
  for (int j = 0; j < 4; ++j)
    #pragma unroll
    for (int ks = 0; ks < 2; ++ks)
      qf[j][ks] = *(const bf16x8*)(qbase + (size_t)j*16*1536 + ks*32);

  // mask -> bitmask (thread t handles row p=t); dtype detect i32 vs bytes
  const unsigned* mwords = (const unsigned*)mask;
  bool is_i32 = true;
  #pragma unroll
  for (int i = 0; i < 16; ++i) is_i32 = is_i32 && (mwords[i] <= 1u);
  if (is_i32) {
    const uint4* mr4 = (const uint4*)(mwords + ((size_t)g*PD + tid)*PD);
    #pragma unroll
    for (int w = 0; w < 8; ++w) {
      unsigned bits = 0;
      #pragma unroll
      for (int j = 0; j < 8; ++j) {
        uint4 m4 = mr4[w*8 + j];
        bits |= (m4.x ? 1u : 0u) << (j*4+0);
        bits |= (m4.y ? 1u : 0u) << (j*4+1);
        bits |= (m4.z ? 1u : 0u) << (j*4+2);
        bits |= (m4.w ? 1u : 0u) << (j*4+3);
      }
      mb[tid][w] = bits;
    }
  } else {
    const unsigned* mr = (const unsigned*)(mask + ((size_t)g*PD + tid)*PD);
    #pragma unroll
    for (int w = 0; w < 8; ++w) {
      unsigned bits = 0;
      #pragma unroll
      for (int j = 0; j < 8; ++j) {
        unsigned vv = mr[w*8 + j];
        if (vv & 0x000000FFu) bits |= 1u << (j*4+0);
        if (vv & 0x0000FF00u) bits |= 1u << (j*4+1);
        if (vv & 0x00FF0000u) bits |= 1u << (j*4+2);
        if (vv & 0xFF000000u) bits |= 1u << (j*4+3);
      }
      mb[tid][w] = bits;
    }
  }
  __syncthreads();   // only barrier in the kernel

  const __bf16* kbase = qk + (size_t)(g*PD + l15) * 1536 + D_ + h*HDD + t4*8;
  const _Float16* vb  = vbuf + (size_t)(h*HDD + l15) * vcols + (size_t)b*NGP + g*PD + t4*8;
  _Float16* pw = &p_lds[wave][0];

  float rm[4], rl[4];
  #pragma unroll
  for (int j = 0; j < 4; ++j) { rm[j] = -1e30f; rl[j] = 0.f; }
  f32x4 o[4][4] = {};   // [hd-frag][p-frag]

  for (int qt = 0; qt < 4; ++qt) {
    // ---- S^T tile = K . Q^T (already scaled, log2 domain) ----
    bf16x8 kf[4][2];
    #pragma unroll
    for (int i = 0; i < 4; ++i)
      #pragma unroll
      for (int ks = 0; ks < 2; ++ks)
        kf[i][ks] = *(const bf16x8*)(kbase + (size_t)(qt*64 + i*16)*1536 + ks*32);
    f32x4 s[4][4] = {};  // [q-frag][p-frag]
    #pragma unroll
    for (int ks = 0; ks < 2; ++ks)
      #pragma unroll
      for (int i = 0; i < 4; ++i)
        #pragma unroll
        for (int j = 0; j < 4; ++j)
          s[i][j] = __builtin_amdgcn_mfma_f32_16x16x32_bf16(kf[i][ks], qf[j][ks], s[i][j], 0, 0, 0);

    // ---- V fragments issued early: HBM/L2 latency hides under softmax ----
    f16x8 vf[4][2];
    #pragma unroll
    for (int i2 = 0; i2 < 4; ++i2)
      #pragma unroll
      for (int ks = 0; ks < 2; ++ks)
        vf[i2][ks] = *(const f16x8*)(vb + (size_t)i2*16*vcols + qt*64 + ks*32);

    // ---- masked online softmax per p-column (j, l15); q spans (i, t4, r) ----
    #pragma unroll
    for (int j = 0; j < 4; ++j) {
      const int pl = wave*64 + j*16 + l15;
      const unsigned w0 = mb[pl][qt*2 + 0], w1 = mb[pl][qt*2 + 1];
      float mxj = -1e30f;
      #pragma unroll
      for (int i = 0; i < 4; ++i) {
        const unsigned w = (i < 2) ? w0 : w1;
        const int base = (i & 1)*16 + t4*4;
        #pragma unroll
        for (int r = 0; r < 4; ++r) {
          float sv = ((w >> (base + r)) & 1u) ? s[i][j][r] : -1e30f;
          s[i][j][r] = sv;
          mxj = fmaxf(mxj, sv);
        }
      }
      mxj = fmaxf(mxj, __shfl_xor(mxj, 16, 64));
      mxj = fmaxf(mxj, __shfl_xor(mxj, 32, 64));
      // T13 defer-max: skip rescale while tile max stays within 2^8 of running max
      const bool defer = __all(mxj <= rm[j] + 8.f);
      const float mnew = defer ? rm[j] : fmaxf(rm[j], mxj);
      const float mneg = -mnew;
      float rs = 0.f;
      #pragma unroll
      for (int i = 0; i < 4; ++i)
        #pragma unroll
        for (int r = 0; r < 4; ++r) {
          float e = exp2_fast(s[i][j][r] + mneg);   // masked: -1e30 -> 0
          s[i][j][r] = e;
          rs += e;
        }
      rs += __shfl_xor(rs, 16, 64);
      rs += __shfl_xor(rs, 32, 64);
      if (defer) {
        rl[j] += rs;
      } else {
        const float scl = exp2_fast(rm[j] - mnew);
        rl[j] = fmaf(rl[j], scl, rs);
        #pragma unroll
        for (int i2 = 0; i2 < 4; ++i2)
          #pragma unroll
          for (int r = 0; r < 4; ++r)
            o[i2][j][r] *= scl;
        rm[j] = mnew;
      }
      // P column-block j -> LDS f16, chunk layout: lane-linear fragment reads
      #pragma unroll
      for (int i = 0; i < 4; ++i) {
        f16x4 pk;
        #pragma unroll
        for (int r = 0; r < 4; ++r) pk[r] = (_Float16)s[i][j][r];
        *(f16x4*)&pw[j*1024 + (2*i + (t4 >> 1))*128 + l15*8 + 4*(t4 & 1)] = pk;
      }
    }

    // ---- O^T += V^T . P^T ---- (per-wave LDS: in-order DS makes RAW safe, no barrier)
    f16x8 pf[4][2];
    #pragma unroll
    for (int j2 = 0; j2 < 4; ++j2)
      #pragma unroll
      for (int ks = 0; ks < 2; ++ks)
        pf[j2][ks] = *(const f16x8*)&pw[j2*1024 + (4*ks + t4)*128 + l15*8];
    #pragma unroll
    for (int ks = 0; ks < 2; ++ks)
      #pragma unroll
      for (int i2 = 0; i2 < 4; ++i2)
        #pragma unroll
        for (int j2 = 0; j2 < 4; ++j2)
          o[i2][j2] = __builtin_amdgcn_mfma_f32_16x16x32_f16(vf[i2][ks], pf[j2][ks], o[i2][j2], 0, 0, 0);
  }

  // ---- epilogue ----
  #pragma unroll
  for (int j2 = 0; j2 < 4; ++j2) {
    const float inv = 1.f / rl[j2];
    __bf16* ao = aot + ((size_t)b*NGP + g*PD + wave*64 + j2*16 + l15) * D_ + h*HDD;
    #pragma unroll
    for (int i2 = 0; i2 < 4; ++i2) {
      bf16x4 ov;
      #pragma unroll
      for (int r = 0; r < 4; ++r) ov[r] = (__bf16)(o[i2][j2][r] * inv);
      *(bf16x4*)(ao + i2*16 + t4*4) = ov;
    }
  }
}

extern "C" void kernel_launch(void* const* d_in, const int* in_sizes, int n_in,
                              void* d_out, int out_size, void* d_ws, size_t ws_size,
                              hipStream_t stream) {
  const float* x      = (const float*)d_in[0];
  const unsigned char* mask = (const unsigned char*)d_in[1];
  const float* w_qkv  = (const float*)d_in[2];
  const float* w_proj = (const float*)d_in[3];
  const float* b_proj = (const float*)d_in[4];
  float* out = (float*)d_out;

  // batched workspace layout (bytes):
  const size_t sz_qkT = (size_t)NB * NGP * 1536 * 2;  // 201.3 MB
  const size_t sz_v   = (size_t)D_ * NB * NGP * 2;    // 100.7 MB
  const size_t sz_xt  = (size_t)NB * NGP * D_ * 2;    // 100.7 MB
  const size_t sz_aot = (size_t)NB * NGP * D_ * 2;    // 100.7 MB
  const size_t sz_wq  = (size_t)3 * D_ * D_ * 2;
  const size_t sz_wp  = (size_t)D_ * D_ * 2;
  const size_t need_big = sz_qkT + sz_v + sz_xt + sz_aot + sz_wq + sz_wp; // ~485 MiB

  const bool big = ws_size >= need_big;

  char* ws = (char*)d_ws;
  __bf16*   qkT  = (__bf16*)ws;    ws += big ? sz_qkT : (size_t)NGP*1536*2;
  _Float16* vf16 = (_Float16*)ws;  ws += big ? sz_v   : (size_t)D_*NGP*2;
  __bf16*   xt   = (__bf16*)ws;    ws += big ? sz_xt  : (size_t)NGP*D_*2;
  __bf16*   aot  = (__bf16*)ws;    ws += big ? sz_aot : (size_t)NGP*D_*2;
  __bf16*   wq_bf= (__bf16*)ws;    ws += sz_wq;
  __bf16*   wp_bf= (__bf16*)ws;

  // Q-weight rows (first 768) pre-scaled by SCALE*log2e -> MFMA S is log2-domain
  wcast_k<<<(3*D_*D_)/1024, 256, 0, stream>>>(w_qkv,  wq_bf, 3*D_*D_, D_*D_, QPRE);
  wcast_k<<<(D_*D_)/1024,   256, 0, stream>>>(w_proj, wp_bf, D_*D_, 0, 1.f);

  if (big) {
    const int NCOL = NB * NGP;  // 65536
    tcast_k<<<dim3(NGP/64, D_/32, NB), 256, 0, stream>>>(x, xt);
    // qkT[b*gp][1536] = xt . w_qk^T
    mfma_gemm<0,1,0><<<dim3(1536/128, NCOL/128), 256, 0, stream>>>(xt, wq_bf, nullptr, qkT, NCOL, 1536, D_);
    // v[768][b*gp] f16 = w_v . xt^T
    mfma_gemm<0,2,0><<<dim3(NCOL/128, D_/128), 256, 0, stream>>>(wq_bf + (size_t)1536*D_, xt, nullptr, vf16, D_, NCOL, D_);
    attn_mfma<<<dim3(GD, HH, NB), 256, 0, stream>>>(qkT, vf16, mask, aot, NCOL);
    // out[b][768][gp] f32 = w_p . aot^T + bias (batched column remap)
    mfma_gemm<1,0,1><<<dim3(NCOL/128, D_/128), 256, 0, stream>>>(wp_bf, aot, b_proj, out, D_, NCOL, D_);
  } else {
    for (int b = 0; b < NB; ++b) {
      const float* xb = x + (size_t)b * D_ * NGP;
      float* ob = out + (size_t)b * D_ * NGP;
      tcast_k<<<dim3(NGP/64, D_/32, 1), 256, 0, stream>>>(xb, xt);
      mfma_gemm<0,1,0><<<dim3(1536/128, NGP/128), 256, 0, stream>>>(xt, wq_bf, nullptr, qkT, NGP, 1536, D_);
      mfma_gemm<0,2,0><<<dim3(NGP/128, D_/128), 256, 0, stream>>>(wq_bf + (size_t)1536*D_, xt, nullptr, vf16, D_, NGP, D_);
      attn_mfma<<<dim3(GD, HH, 1), 256, 0, stream>>>(qkT, vf16, mask, aot, NGP);
      mfma_gemm<1,0,0><<<dim3(NGP/128, D_/128), 256, 0, stream>>>(wp_bf, aot, b_proj, ob, D_, NGP, D_);
    }
  }
}

// Round 4
// 1074.517 us; speedup vs baseline: 2.3095x; 1.1007x over previous
//
#include <hip/hip_runtime.h>
#include <float.h>

#define D_    768
#define GD    64
#define PD    256
#define HH    12
#define HDD   64
#define NGP   (GD*PD)   // 16384
#define NB    4
#define SCALE 0.125f
#define QPRE  (0.125f * 1.44269504f)   // SCALE*log2(e), folded into Q weights

typedef __bf16 bf16x8 __attribute__((ext_vector_type(8)));
typedef __bf16 bf16x4 __attribute__((ext_vector_type(4)));
typedef _Float16 f16x8 __attribute__((ext_vector_type(8)));
typedef _Float16 f16x4 __attribute__((ext_vector_type(4)));
typedef float  f32x4  __attribute__((ext_vector_type(4)));

__device__ __forceinline__ float exp2_fast(float x) {
  return __builtin_amdgcn_exp2f(x);   // v_exp_f32: native 2^x
}

__device__ __forceinline__ void gload_lds16(const __bf16* g, __bf16* l) {
  __builtin_amdgcn_global_load_lds(
      (const __attribute__((address_space(1))) void*)g,
      (__attribute__((address_space(3))) void*)l, 16, 0, 0);
}

__device__ __forceinline__ unsigned short f2bf_bits(float f) {
  __bf16 h = (__bf16)f;
  unsigned short u;
  __builtin_memcpy(&u, &h, 2);
  return u;
}

// ---------------- fp32 -> bf16 cast; first nscale elements premultiplied by sc ----------------
__global__ void wcast_k(const float* __restrict__ in, __bf16* __restrict__ out, int n,
                        int nscale, float sc) {
  int i = (blockIdx.x * 256 + threadIdx.x) * 4;
  if (i >= n) return;
  float s = (i < nscale) ? sc : 1.f;
  float4 v = *(const float4*)(in + i);
  bf16x4 o;
  o[0] = (__bf16)(v.x * s); o[1] = (__bf16)(v.y * s);
  o[2] = (__bf16)(v.z * s); o[3] = (__bf16)(v.w * s);
  *(bf16x4*)(out + i) = o;
}

// ---------------- mask -> bitmap, once per session: gbm[g][p][8] u32 ----------------
__global__ void maskpack_k(const unsigned char* __restrict__ mask, unsigned* __restrict__ gbm) {
  const int g = blockIdx.x, p = threadIdx.x;
  const unsigned* mwords = (const unsigned*)mask;
  bool is_i32 = true;
  #pragma unroll
  for (int i = 0; i < 16; ++i) is_i32 = is_i32 && (mwords[i] <= 1u);
  unsigned* o = gbm + ((size_t)g * PD + p) * 8;
  if (is_i32) {
    const uint4* mr4 = (const uint4*)(mwords + ((size_t)g * PD + p) * PD);
    #pragma unroll
    for (int w = 0; w < 8; ++w) {
      unsigned bits = 0;
      #pragma unroll
      for (int j = 0; j < 8; ++j) {
        uint4 m4 = mr4[w*8 + j];
        bits |= (m4.x ? 1u : 0u) << (j*4+0);
        bits |= (m4.y ? 1u : 0u) << (j*4+1);
        bits |= (m4.z ? 1u : 0u) << (j*4+2);
        bits |= (m4.w ? 1u : 0u) << (j*4+3);
      }
      o[w] = bits;
    }
  } else {
    const unsigned* mr = (const unsigned*)(mask + ((size_t)g * PD + p) * PD);
    #pragma unroll
    for (int w = 0; w < 8; ++w) {
      unsigned bits = 0;
      #pragma unroll
      for (int j = 0; j < 8; ++j) {
        unsigned vv = mr[w*8 + j];
        if (vv & 0x000000FFu) bits |= 1u << (j*4+0);
        if (vv & 0x0000FF00u) bits |= 1u << (j*4+1);
        if (vv & 0x00FF0000u) bits |= 1u << (j*4+2);
        if (vv & 0xFF000000u) bits |= 1u << (j*4+3);
      }
      o[w] = bits;
    }
  }
}

// ---------------- transpose-cast: in[768][16384] f32 -> out[16384][768] bf16 (per batch z) ----------------
__global__ void tcast_k(const float* __restrict__ in, __bf16* __restrict__ out) {
  __shared__ float s[32][66];
  const int tid = threadIdx.x;
  const int c0 = blockIdx.x * 64;
  const int r0 = blockIdx.y * 32;
  const float* inz = in + (size_t)blockIdx.z * D_ * NGP;
  unsigned* outu = (unsigned*)out + (size_t)blockIdx.z * NGP * (D_ / 2);
  const int lx = tid & 63, ly = tid >> 6;
  #pragma unroll
  for (int rr = 0; rr < 32; rr += 4)
    s[rr + ly][lx] = inz[(size_t)(r0 + rr + ly) * NGP + c0 + lx];
  __syncthreads();
  const int wx = tid & 15, wy = tid >> 4;
  #pragma unroll
  for (int p = 0; p < 64; p += 16) {
    int j = p + wy;
    unsigned pk = (unsigned)f2bf_bits(s[2*wx][j]) |
                  ((unsigned)f2bf_bits(s[2*wx+1][j]) << 16);
    outu[(size_t)(c0 + j) * (D_/2) + (r0 >> 1) + wx] = pk;
  }
}

// ---------------- MFMA GEMM: C[M,N] = A[M,K] * Bt[N,K]^T (+bias), BK=64 ----------------
// OUT: 0=f32, 1=bf16, 2=f16. OUTB: remap col c -> out[b= c>>14][row][gp= c&16383] (f32 only).
// LDS: 8 row-groups of 16 rows; group r = 2 KB at r*1024 elems; within group,
// k-half s (32-K) at s*512 elems; 16B chunk = rows m=(l&15), k-chunk (l>>4).
template<int BIAS, int OUT, int OUTB>
__global__ __launch_bounds__(256, 2)
void mfma_gemm(const __bf16* __restrict__ A, const __bf16* __restrict__ Bt,
               const float* __restrict__ bias, void* __restrict__ Cout,
               int M, int N, int K) {
  __shared__ __align__(16) __bf16 As[128 * 64];   // 16 KB
  __shared__ __align__(16) __bf16 Bs[128 * 64];   // 16 KB
  const int tid = threadIdx.x;
  const int wave = tid >> 6, lane = tid & 63;
  const int wm = wave >> 1, wn = wave & 1;
  const int m0 = blockIdx.y * 128, n0 = blockIdx.x * 128;

  const int r0g = wave * 2, r1g = wave * 2 + 1;      // this wave's two staging groups
  const int kch = (lane >> 4) * 8;                   // k offset within 32-half
  const __bf16* gA0 = A  + (size_t)(m0 + r0g * 16 + (lane & 15)) * K + kch;
  const __bf16* gA1 = gA0 + (size_t)16 * K;
  const __bf16* gB0 = Bt + (size_t)(n0 + r0g * 16 + (lane & 15)) * K + kch;
  const __bf16* gB1 = gB0 + (size_t)16 * K;
  __bf16* lA0 = As + r0g * 1024;  __bf16* lA1 = As + r1g * 1024;
  __bf16* lB0 = Bs + r0g * 1024;  __bf16* lB1 = Bs + r1g * 1024;

  f32x4 acc[4][4] = {};
  const bf16x8* Av = (const bf16x8*)As;
  const bf16x8* Bv = (const bf16x8*)Bs;

  for (int k0 = 0; k0 < K; k0 += 64) {
    __syncthreads();                 // previous iter's LDS reads complete
    gload_lds16(gA0, lA0);  gload_lds16(gA0 + 32, lA0 + 512);
    gload_lds16(gA1, lA1);  gload_lds16(gA1 + 32, lA1 + 512);
    gload_lds16(gB0, lB0);  gload_lds16(gB0 + 32, lB0 + 512);
    gload_lds16(gB1, lB1);  gload_lds16(gB1 + 32, lB1 + 512);
    gA0 += 64; gA1 += 64; gB0 += 64; gB1 += 64;
    __syncthreads();                 // drains vmcnt(0): tiles ready
    #pragma unroll
    for (int s = 0; s < 2; ++s) {
      bf16x8 af[4], bf[4];
      #pragma unroll
      for (int i = 0; i < 4; ++i) af[i] = Av[(wm * 4 + i) * 128 + s * 64 + lane];
      #pragma unroll
      for (int j = 0; j < 4; ++j) bf[j] = Bv[(wn * 4 + j) * 128 + s * 64 + lane];
      #pragma unroll
      for (int i = 0; i < 4; ++i)
        #pragma unroll
        for (int j = 0; j < 4; ++j)
          acc[i][j] = __builtin_amdgcn_mfma_f32_16x16x32_bf16(af[i], bf[j], acc[i][j], 0, 0, 0);
    }
  }

  #pragma unroll
  for (int i = 0; i < 4; ++i) {
    #pragma unroll
    for (int j = 0; j < 4; ++j) {
      const int col  = n0 + wn * 64 + j * 16 + (lane & 15);
      const int row0 = m0 + wm * 64 + i * 16 + (lane >> 4) * 4;
      #pragma unroll
      for (int r = 0; r < 4; ++r) {
        float v = acc[i][j][r];
        if (BIAS) v += bias[row0 + r];
        if (OUT == 1)
          ((__bf16*)Cout)[(size_t)(row0 + r) * N + col] = (__bf16)v;
        else if (OUT == 2)
          ((_Float16*)Cout)[(size_t)(row0 + r) * N + col] = (_Float16)v;
        else if (OUTB) {
          const int bb = col >> 14, gp = col & (NGP - 1);
          ((float*)Cout)[((size_t)bb * D_ + row0 + r) * NGP + gp] = v;
        } else
          ((float*)Cout)[(size_t)(row0 + r) * N + col] = v;
      }
    }
  }
}

// ---------------- MFMA flash attention ----------------
// qkT [b][16384][1536] bf16 (Q channels pre-scaled by SCALE*log2e), vbuf [768][vcols] f16,
// gbm [g][p][8] packed mask bits. Block (g,h,b); 4 waves, wave owns 64 p-columns.
//   S^T = K . Q^T   (softmax stats per lane-column, log2 domain)
//   O^T = V^T . P^T (rows hd -> packs into aot[gp][ch])
__global__ __launch_bounds__(256, 2)
void attn_mfma(const __bf16* __restrict__ qkT, const _Float16* __restrict__ vbuf,
               const unsigned* __restrict__ gbm, __bf16* __restrict__ aot,
               int vcols) {
  __shared__ unsigned mb[256][9];                    // [p][q/32] bitmap, padded stride
  __shared__ __align__(16) _Float16 p_lds[4][4096];  // per-wave P tile

  const int g = blockIdx.x, h = blockIdx.y, b = blockIdx.z;
  const int tid = threadIdx.x;
  const int wave = tid >> 6, lane = tid & 63;
  const int l15 = lane & 15, t4 = lane >> 4;

  const __bf16* qk = qkT + (size_t)b * NGP * 1536;

  // Q fragments (B-operand) — resident all kernel
  const __bf16* qbase = qk + (size_t)(g*PD + wave*64 + l15) * 1536 + h*HDD + t4*8;
  bf16x8 qf[4][2];
  #pragma unroll
  for (int j = 0; j < 4; ++j)
    #pragma unroll
    for (int ks = 0; ks < 2; ++ks)
      qf[j][ks] = *(const bf16x8*)(qbase + (size_t)j*16*1536 + ks*32);

  // pre-packed mask row -> LDS bitmap (8 KB/block instead of 262 KB)
  {
    const uint4* gbr = (const uint4*)(gbm + ((size_t)g * PD + tid) * 8);
    uint4 w0 = gbr[0], w1 = gbr[1];
    mb[tid][0] = w0.x; mb[tid][1] = w0.y; mb[tid][2] = w0.z; mb[tid][3] = w0.w;
    mb[tid][4] = w1.x; mb[tid][5] = w1.y; mb[tid][6] = w1.z; mb[tid][7] = w1.w;
  }
  __syncthreads();   // only barrier in the kernel

  const __bf16* kbase = qk + (size_t)(g*PD + l15) * 1536 + D_ + h*HDD + t4*8;
  const _Float16* vb  = vbuf + (size_t)(h*HDD + l15) * vcols + (size_t)b*NGP + g*PD + t4*8;
  _Float16* pw = &p_lds[wave][0];

  float rm[4], rl[4];
  #pragma unroll
  for (int j = 0; j < 4; ++j) { rm[j] = -1e30f; rl[j] = 0.f; }
  f32x4 o[4][4] = {};   // [hd-frag][p-frag]

  for (int qt = 0; qt < 4; ++qt) {
    // ---- S^T tile = K . Q^T (already scaled, log2 domain) ----
    bf16x8 kf[4][2];
    #pragma unroll
    for (int i = 0; i < 4; ++i)
      #pragma unroll
      for (int ks = 0; ks < 2; ++ks)
        kf[i][ks] = *(const bf16x8*)(kbase + (size_t)(qt*64 + i*16)*1536 + ks*32);
    f32x4 s[4][4] = {};  // [q-frag][p-frag]
    #pragma unroll
    for (int ks = 0; ks < 2; ++ks)
      #pragma unroll
      for (int i = 0; i < 4; ++i)
        #pragma unroll
        for (int j = 0; j < 4; ++j)
          s[i][j] = __builtin_amdgcn_mfma_f32_16x16x32_bf16(kf[i][ks], qf[j][ks], s[i][j], 0, 0, 0);

    // ---- V fragments issued early: HBM/L2 latency hides under softmax ----
    f16x8 vf[4][2];
    #pragma unroll
    for (int i2 = 0; i2 < 4; ++i2)
      #pragma unroll
      for (int ks = 0; ks < 2; ++ks)
        vf[i2][ks] = *(const f16x8*)(vb + (size_t)i2*16*vcols + qt*64 + ks*32);

    // ---- masked online softmax per p-column (j, l15); q spans (i, t4, r) ----
    #pragma unroll
    for (int j = 0; j < 4; ++j) {
      const int pl = wave*64 + j*16 + l15;
      const unsigned w0 = mb[pl][qt*2 + 0], w1 = mb[pl][qt*2 + 1];
      float mxj = -1e30f;
      #pragma unroll
      for (int i = 0; i < 4; ++i) {
        const unsigned w = (i < 2) ? w0 : w1;
        const int base = (i & 1)*16 + t4*4;
        #pragma unroll
        for (int r = 0; r < 4; ++r) {
          float sv = ((w >> (base + r)) & 1u) ? s[i][j][r] : -1e30f;
          s[i][j][r] = sv;
          mxj = fmaxf(mxj, sv);
        }
      }
      mxj = fmaxf(mxj, __shfl_xor(mxj, 16, 64));
      mxj = fmaxf(mxj, __shfl_xor(mxj, 32, 64));
      // T13 defer-max: skip rescale while tile max stays within 2^8 of running max
      const bool defer = __all(mxj <= rm[j] + 8.f);
      const float mnew = defer ? rm[j] : fmaxf(rm[j], mxj);
      const float mneg = -mnew;
      float rs = 0.f;
      #pragma unroll
      for (int i = 0; i < 4; ++i)
        #pragma unroll
        for (int r = 0; r < 4; ++r) {
          float e = exp2_fast(s[i][j][r] + mneg);   // masked: -1e30 -> 0
          s[i][j][r] = e;
          rs += e;
        }
      rs += __shfl_xor(rs, 16, 64);
      rs += __shfl_xor(rs, 32, 64);
      if (defer) {
        rl[j] += rs;
      } else {
        const float scl = exp2_fast(rm[j] - mnew);
        rl[j] = fmaf(rl[j], scl, rs);
        #pragma unroll
        for (int i2 = 0; i2 < 4; ++i2)
          #pragma unroll
          for (int r = 0; r < 4; ++r)
            o[i2][j][r] *= scl;
        rm[j] = mnew;
      }
      // P column-block j -> LDS f16, chunk layout: lane-linear fragment reads
      #pragma unroll
      for (int i = 0; i < 4; ++i) {
        f16x4 pk;
        #pragma unroll
        for (int r = 0; r < 4; ++r) pk[r] = (_Float16)s[i][j][r];
        *(f16x4*)&pw[j*1024 + (2*i + (t4 >> 1))*128 + l15*8 + 4*(t4 & 1)] = pk;
      }
    }

    // ---- O^T += V^T . P^T ---- (per-wave LDS: in-order DS makes RAW safe, no barrier)
    f16x8 pf[4][2];
    #pragma unroll
    for (int j2 = 0; j2 < 4; ++j2)
      #pragma unroll
      for (int ks = 0; ks < 2; ++ks)
        pf[j2][ks] = *(const f16x8*)&pw[j2*1024 + (4*ks + t4)*128 + l15*8];
    #pragma unroll
    for (int ks = 0; ks < 2; ++ks)
      #pragma unroll
      for (int i2 = 0; i2 < 4; ++i2)
        #pragma unroll
        for (int j2 = 0; j2 < 4; ++j2)
          o[i2][j2] = __builtin_amdgcn_mfma_f32_16x16x32_f16(vf[i2][ks], pf[j2][ks], o[i2][j2], 0, 0, 0);
  }

  // ---- epilogue ----
  #pragma unroll
  for (int j2 = 0; j2 < 4; ++j2) {
    const float inv = 1.f / rl[j2];
    __bf16* ao = aot + ((size_t)b*NGP + g*PD + wave*64 + j2*16 + l15) * D_ + h*HDD;
    #pragma unroll
    for (int i2 = 0; i2 < 4; ++i2) {
      bf16x4 ov;
      #pragma unroll
      for (int r = 0; r < 4; ++r) ov[r] = (__bf16)(o[i2][j2][r] * inv);
      *(bf16x4*)(ao + i2*16 + t4*4) = ov;
    }
  }
}

extern "C" void kernel_launch(void* const* d_in, const int* in_sizes, int n_in,
                              void* d_out, int out_size, void* d_ws, size_t ws_size,
                              hipStream_t stream) {
  const float* x      = (const float*)d_in[0];
  const unsigned char* mask = (const unsigned char*)d_in[1];
  const float* w_qkv  = (const float*)d_in[2];
  const float* w_proj = (const float*)d_in[3];
  const float* b_proj = (const float*)d_in[4];
  float* out = (float*)d_out;

  // batched workspace layout (bytes):
  const size_t sz_qkT = (size_t)NB * NGP * 1536 * 2;  // 201.3 MB
  const size_t sz_v   = (size_t)D_ * NB * NGP * 2;    // 100.7 MB
  const size_t sz_xt  = (size_t)NB * NGP * D_ * 2;    // 100.7 MB
  const size_t sz_aot = (size_t)NB * NGP * D_ * 2;    // 100.7 MB
  const size_t sz_wq  = (size_t)3 * D_ * D_ * 2;
  const size_t sz_wp  = (size_t)D_ * D_ * 2;
  const size_t sz_gbm = (size_t)GD * PD * 8 * 4;      // 512 KB
  const size_t need_big = sz_qkT + sz_v + sz_xt + sz_aot + sz_wq + sz_wp + sz_gbm;

  const bool big = ws_size >= need_big;

  char* ws = (char*)d_ws;
  __bf16*   qkT  = (__bf16*)ws;    ws += big ? sz_qkT : (size_t)NGP*1536*2;
  _Float16* vf16 = (_Float16*)ws;  ws += big ? sz_v   : (size_t)D_*NGP*2;
  __bf16*   xt   = (__bf16*)ws;    ws += big ? sz_xt  : (size_t)NGP*D_*2;
  __bf16*   aot  = (__bf16*)ws;    ws += big ? sz_aot : (size_t)NGP*D_*2;
  __bf16*   wq_bf= (__bf16*)ws;    ws += sz_wq;
  __bf16*   wp_bf= (__bf16*)ws;    ws += sz_wp;
  unsigned* gbm  = (unsigned*)ws;

  // Q-weight rows (first 768) pre-scaled by SCALE*log2e -> MFMA S is log2-domain
  wcast_k<<<(3*D_*D_)/1024, 256, 0, stream>>>(w_qkv,  wq_bf, 3*D_*D_, D_*D_, QPRE);
  wcast_k<<<(D_*D_)/1024,   256, 0, stream>>>(w_proj, wp_bf, D_*D_, 0, 1.f);
  maskpack_k<<<GD, PD, 0, stream>>>(mask, gbm);

  if (big) {
    const int NCOL = NB * NGP;  // 65536
    tcast_k<<<dim3(NGP/64, D_/32, NB), 256, 0, stream>>>(x, xt);
    // qkT[b*gp][1536] = xt . w_qk^T
    mfma_gemm<0,1,0><<<dim3(1536/128, NCOL/128), 256, 0, stream>>>(xt, wq_bf, nullptr, qkT, NCOL, 1536, D_);
    // v[768][b*gp] f16 = w_v . xt^T
    mfma_gemm<0,2,0><<<dim3(NCOL/128, D_/128), 256, 0, stream>>>(wq_bf + (size_t)1536*D_, xt, nullptr, vf16, D_, NCOL, D_);
    attn_mfma<<<dim3(GD, HH, NB), 256, 0, stream>>>(qkT, vf16, gbm, aot, NCOL);
    // out[b][768][gp] f32 = w_p . aot^T + bias (batched column remap)
    mfma_gemm<1,0,1><<<dim3(NCOL/128, D_/128), 256, 0, stream>>>(wp_bf, aot, b_proj, out, D_, NCOL, D_);
  } else {
    for (int b = 0; b < NB; ++b) {
      const float* xb = x + (size_t)b * D_ * NGP;
      float* ob = out + (size_t)b * D_ * NGP;
      tcast_k<<<dim3(NGP/64, D_/32, 1), 256, 0, stream>>>(xb, xt);
      mfma_gemm<0,1,0><<<dim3(1536/128, NGP/128), 256, 0, stream>>>(xt, wq_bf, nullptr, qkT, NGP, 1536, D_);
      mfma_gemm<0,2,0><<<dim3(NGP/128, D_/128), 256, 0, stream>>>(wq_bf + (size_t)1536*D_, xt, nullptr, vf16, D_, NGP, D_);
      attn_mfma<<<dim3(GD, HH, 1), 256, 0, stream>>>(qkT, vf16, gbm, aot, NGP);
      mfma_gemm<1,0,0><<<dim3(NGP/128, D_/128), 256, 0, stream>>>(wp_bf, aot, b_proj, ob, D_, NGP, D_);
    }
  }
}